// Round 6
// baseline (278.689 us; speedup 1.0000x reference)
//
#include <hip/hip_runtime.h>
#include <hip/hip_bf16.h>
#include <float.h>
#include <math.h>

// Problem constants (B, L, H, D fixed by the reference setup)
constexpr int B = 4;
constexpr int L = 2048;
constexpr int H = 16;
constexpr int D = 64;
constexpr int U = 40;   // u_top = min(5*ceil(ln(2048)), 2048) = 40
constexpr int UG = 8;   // u's per pv block
constexpr int NCH = 8;  // L-chunks per (b,h) in scores kernel (256 rows each)
constexpr int LPB = 16; // l's per block in compute_M
constexpr int RCH = 8;  // row chunks (256 rows each) in pv_partial

// Fused grid: groups of 8 blocks; every 5th group copies, rest compute M.
// 1280 groups total = 1024 M-groups (8192 blocks) + 256 copy-groups (2048 blocks).
constexpr int NGRP = 1280;
constexpr int CPBLK = 2048;

typedef float floatx4 __attribute__((ext_vector_type(4)));

__device__ inline float dot8(floatx4 a0, floatx4 a1, floatx4 b0, floatx4 b1) {
    return a0.x * b0.x + a0.y * b0.y + a0.z * b0.z + a0.w * b0.w
         + a1.x * b1.x + a1.y * b1.y + a1.z * b1.z + a1.w * b1.w;
}

// ---------------------------------------------------------------------------
// Fused kernel: copy groups interleaved among M groups so HBM copy overlaps
// the L2-bound gather. M part: wave handles 4 l's, processed in independent
// pairs for 2x memory-level parallelism. lane = g8*8 + dpart; sample
// s = i*8 + g8; each lane dots 8 elems of D (two float4, full-line loads).
// ---------------------------------------------------------------------------
template<int SKC>
__global__ void fused_copy_M_kernel(const float* __restrict__ q, const float* __restrict__ k,
                                    const float* __restrict__ v, const int* __restrict__ sidx,
                                    float* __restrict__ out, float* __restrict__ M, int n4) {
    int blk = blockIdx.x;
    int t = threadIdx.x;
    int grp = blk >> 3;
    int sub = blk & 7;

    if (grp % 5 == 4) {
        // ---- copy part ----
        int cblk = (grp / 5) * 8 + sub;
        int i = cblk * 256 + t;
        int stride = CPBLK * 256;
        const floatx4* src = reinterpret_cast<const floatx4*>(v);
        floatx4* dst = reinterpret_cast<floatx4*>(out);
        for (; i < n4; i += stride) {
            floatx4 x = __builtin_nontemporal_load(src + i);
            __builtin_nontemporal_store(x, dst + i);
        }
        return;
    }

    // ---- compute-M part ----
    int mgroup = (grp / 5) * 4 + (grp % 5);   // 0..1023
    int xcd = sub;                            // blk%8 == XCD (empirical RR)
    int bh = (mgroup & 7) * 8 + xcd;          // bh%8 == blk%8 (XCD affinity)
    int chunk = mgroup >> 3;                  // 0..127
    int b = bh >> 4, h = bh & 15;

    __shared__ int s_idx[LPB * SKC];
    for (int i = t; i < LPB * SKC; i += 256)
        s_idx[i] = sidx[(size_t)chunk * LPB * SKC + i];
    __syncthreads();

    int w = t >> 6;
    int lane = t & 63;
    int g8 = lane >> 3;     // sample group 0..7
    int dpart = lane & 7;   // 8-elem slice of D

    #pragma unroll
    for (int li = 0; li < 4; li += 2) {
        int lga = w * 4 + li;
        int lgb = lga + 1;
        int la = chunk * LPB + lga;
        int lb = la + 1;

        const float* qra = q + ((size_t)(b * L + la) * H + h) * D;
        const float* qrb = q + ((size_t)(b * L + lb) * H + h) * D;
        floatx4 qa0 = *reinterpret_cast<const floatx4*>(qra + dpart * 4);
        floatx4 qa1 = *reinterpret_cast<const floatx4*>(qra + 32 + dpart * 4);
        floatx4 qb0 = *reinterpret_cast<const floatx4*>(qrb + dpart * 4);
        floatx4 qb1 = *reinterpret_cast<const floatx4*>(qrb + 32 + dpart * 4);

        int sa[SKC / 8], sb[SKC / 8];
        #pragma unroll
        for (int i = 0; i < SKC / 8; ++i) {
            sa[i] = s_idx[lga * SKC + i * 8 + g8];
            sb[i] = s_idx[lgb * SKC + i * 8 + g8];
        }

        float mxa = -FLT_MAX, sma = 0.f;
        float mxb = -FLT_MAX, smb = 0.f;
        #pragma unroll
        for (int i = 0; i < SKC / 8; ++i) {
            const float* kra = k + ((size_t)(b * L + sa[i]) * H + h) * D;
            const float* krb = k + ((size_t)(b * L + sb[i]) * H + h) * D;
            floatx4 ka0 = *reinterpret_cast<const floatx4*>(kra + dpart * 4);
            floatx4 ka1 = *reinterpret_cast<const floatx4*>(kra + 32 + dpart * 4);
            floatx4 kb0 = *reinterpret_cast<const floatx4*>(krb + dpart * 4);
            floatx4 kb1 = *reinterpret_cast<const floatx4*>(krb + 32 + dpart * 4);
            float pa = dot8(qa0, qa1, ka0, ka1);
            float pb = dot8(qb0, qb1, kb0, kb1);
            pa += __shfl_xor(pa, 1);  pb += __shfl_xor(pb, 1);
            pa += __shfl_xor(pa, 2);  pb += __shfl_xor(pb, 2);
            pa += __shfl_xor(pa, 4);  pb += __shfl_xor(pb, 4);
            mxa = fmaxf(mxa, pa); sma += pa;
            mxb = fmaxf(mxb, pb); smb += pb;
        }
        #pragma unroll
        for (int off = 8; off <= 32; off <<= 1) {
            mxa = fmaxf(mxa, __shfl_xor(mxa, off)); sma += __shfl_xor(sma, off);
            mxb = fmaxf(mxb, __shfl_xor(mxb, off)); smb += __shfl_xor(smb, off);
        }
        if (lane == 0) {
            M[(size_t)bh * L + la] = mxa - sma * (1.0f / (float)L);
            M[(size_t)bh * L + lb] = mxb - smb * (1.0f / (float)L);
        }
    }
}

// Standalone copy (fallback path)
__global__ void copy_v_kernel(const float* __restrict__ v, float* __restrict__ out, int n4) {
    int i = blockIdx.x * blockDim.x + threadIdx.x;
    int stride = gridDim.x * blockDim.x;
    const floatx4* src = reinterpret_cast<const floatx4*>(v);
    floatx4* dst = reinterpret_cast<floatx4*>(out);
    for (; i < n4; i += stride) {
        floatx4 x = __builtin_nontemporal_load(src + i);
        __builtin_nontemporal_store(x, dst + i);
    }
}

// Fallback M for unexpected SK
__global__ void compute_M_kernel(const float* __restrict__ q, const float* __restrict__ k,
                                 const int* __restrict__ sidx, float* __restrict__ M, int SK) {
    int bl = blockIdx.x;
    int b = bl / L;
    int l = bl % L;
    int t = threadIdx.x;
    int h = t >> 4;
    int dg = t & 15;

    const float* qrow = q + ((size_t)(b * L + l)) * H * D + h * D + dg * 4;
    float4 qv = *reinterpret_cast<const float4*>(qrow);

    float mx = -FLT_MAX;
    float sm = 0.f;
    for (int s = 0; s < SK; ++s) {
        int kidx = sidx[l * SK + s];
        const float* krow = k + ((size_t)(b * L + kidx)) * H * D + h * D + dg * 4;
        float4 kv = *reinterpret_cast<const float4*>(krow);
        float p = qv.x * kv.x + qv.y * kv.y + qv.z * kv.z + qv.w * kv.w;
        #pragma unroll
        for (int off = 8; off >= 1; off >>= 1) p += __shfl_xor(p, off, 16);
        mx = fmaxf(mx, p);
        sm += p;
    }
    if (dg == 0) {
        M[((size_t)(b * H + h)) * L + l] = mx - sm * (1.0f / (float)L);
    }
}

// ---------------------------------------------------------------------------
// Kernel 2 v2: one wave per (b,h), fully register-resident top-U.
// 32 values/lane; per round: register scan + 6-step butterfly (value desc,
// index asc tie-break) + owner-lane invalidate (compile-time reg indices).
// No LDS, no barriers. Same selection sequence as jax.lax.top_k.
// ---------------------------------------------------------------------------
__global__ void topk_wave_kernel(const float* __restrict__ M, int* __restrict__ Mtop) {
    int bh = blockIdx.x;
    int lane = threadIdx.x;  // 0..63
    const float* m = M + (size_t)bh * L;

    float v[32];
    #pragma unroll
    for (int j = 0; j < 32; ++j) v[j] = m[j * 64 + lane];

    for (int u = 0; u < U; ++u) {
        float bv = -FLT_MAX;
        int bi = 0x7fffffff;
        #pragma unroll
        for (int j = 0; j < 32; ++j) {
            int idx = j * 64 + lane;
            bool take = (v[j] > bv) || (v[j] == bv && idx < bi);
            bv = take ? v[j] : bv;
            bi = take ? idx : bi;
        }
        #pragma unroll
        for (int off = 1; off < 64; off <<= 1) {
            float ov = __shfl_xor(bv, off);
            int   oi = __shfl_xor(bi, off);
            bool take = (ov > bv) || (ov == bv && oi < bi);
            bv = take ? ov : bv;
            bi = take ? oi : bi;
        }
        if (lane == 0) Mtop[bh * U + u] = bi;
        #pragma unroll
        for (int j = 0; j < 32; ++j) {
            if (bi == j * 64 + lane) v[j] = -FLT_MAX;
        }
    }
}

// ---------------------------------------------------------------------------
// Kernel 3a: scores. Block = (bh, L-chunk of 256). One thread per key row.
// ---------------------------------------------------------------------------
__global__ void scores_kernel(const float* __restrict__ q, const float* __restrict__ k,
                              const int* __restrict__ Mtop, float* __restrict__ sc) {
    int blk = blockIdx.x;
    int bh = blk >> 3;           // /NCH
    int ch = blk & (NCH - 1);
    int b = bh / H, h = bh % H;
    int t = threadIdx.x;

    __shared__ __align__(16) float qs[U][D];
    for (int i = t; i < U * D; i += 256) {
        int u = i >> 6, dd = i & 63;
        int qi = Mtop[bh * U + u];
        qs[u][dd] = q[((size_t)(b * L + qi)) * H * D + h * D + dd];
    }
    __syncthreads();

    int r = ch * 256 + t;
    const float4* krow = reinterpret_cast<const float4*>(k + ((size_t)(b * L + r)) * H * D + h * D);
    float4 kr[16];
    #pragma unroll
    for (int j = 0; j < 16; ++j) kr[j] = krow[j];

    float* scb = sc + (size_t)bh * U * L;
    for (int u = 0; u < U; ++u) {
        const float4* qrow = reinterpret_cast<const float4*>(qs[u]);
        float acc = 0.f;
        #pragma unroll
        for (int j = 0; j < 16; ++j) {
            float4 qv = qrow[j];
            acc += qv.x * kr[j].x + qv.y * kr[j].y + qv.z * kr[j].z + qv.w * kr[j].w;
        }
        scb[(size_t)u * L + r] = acc * 0.125f;
    }
}

// ---------------------------------------------------------------------------
// Kernel 3b: softmax over each sc row of L. Block per (bh,u). 8 vals/thread.
// ---------------------------------------------------------------------------
__global__ void softmax_kernel(float* __restrict__ sc) {
    int bhu = blockIdx.x;
    float* s = sc + (size_t)bhu * L;
    int t = threadIdx.x;
    __shared__ float redm[4];
    __shared__ float reds[4];

    float4 a = reinterpret_cast<const float4*>(s)[t];
    float4 c = reinterpret_cast<const float4*>(s)[t + 256];

    float m = fmaxf(fmaxf(fmaxf(a.x, a.y), fmaxf(a.z, a.w)),
                    fmaxf(fmaxf(c.x, c.y), fmaxf(c.z, c.w)));
    #pragma unroll
    for (int off = 32; off >= 1; off >>= 1) m = fmaxf(m, __shfl_xor(m, off));
    if ((t & 63) == 0) redm[t >> 6] = m;
    __syncthreads();
    float gm = fmaxf(fmaxf(redm[0], redm[1]), fmaxf(redm[2], redm[3]));

    a.x = __expf(a.x - gm); a.y = __expf(a.y - gm);
    a.z = __expf(a.z - gm); a.w = __expf(a.w - gm);
    c.x = __expf(c.x - gm); c.y = __expf(c.y - gm);
    c.z = __expf(c.z - gm); c.w = __expf(c.w - gm);
    float ls = a.x + a.y + a.z + a.w + c.x + c.y + c.z + c.w;
    #pragma unroll
    for (int off = 32; off >= 1; off >>= 1) ls += __shfl_xor(ls, off);
    if ((t & 63) == 0) reds[t >> 6] = ls;
    __syncthreads();
    float inv = 1.0f / (reds[0] + reds[1] + reds[2] + reds[3]);

    a.x *= inv; a.y *= inv; a.z *= inv; a.w *= inv;
    c.x *= inv; c.y *= inv; c.z *= inv; c.w *= inv;
    reinterpret_cast<float4*>(s)[t] = a;
    reinterpret_cast<float4*>(s)[t + 256] = c;
}

// ---------------------------------------------------------------------------
// Kernel 3c stage 1: partial PV. Block = (bh, ug, rch) = 2560 blocks.
// ---------------------------------------------------------------------------
__global__ void pv_partial_kernel(const float* __restrict__ v, const float* __restrict__ p,
                                  float* __restrict__ partial) {
    int blk = blockIdx.x;
    int xcd = blk & 7;
    int rest = blk >> 3;          // 0..319
    int bh_hi = rest & 7;
    int rest2 = rest >> 3;        // 0..39
    int bh = bh_hi * 8 + xcd;
    int ug = rest2 >> 3;          // /RCH, 0..4
    int rch = rest2 & (RCH - 1);  // 0..7
    int b = bh / H, h = bh % H;
    int t = threadIdx.x;
    int d = t & 63;
    int w = t >> 6;

    const float* pb = p + ((size_t)bh * U + (size_t)ug * UG) * L;
    const float* vb = v + ((size_t)b * L * H + h) * D + d;

    float acc[UG];
    #pragma unroll
    for (int u = 0; u < UG; ++u) acc[u] = 0.f;

    int r0 = rch * 256 + w * 64;
    for (int rr = 0; rr < 64; rr += 2) {
        int r1 = r0 + rr;
        int r2 = r0 + rr + 1;
        float v1 = vb[(size_t)r1 * H * D];
        float v2 = vb[(size_t)r2 * H * D];
        #pragma unroll
        for (int u = 0; u < UG; ++u) {
            float p1 = pb[(size_t)u * L + r1];
            float p2 = pb[(size_t)u * L + r2];
            acc[u] = fmaf(p2, v2, fmaf(p1, v1, acc[u]));
        }
    }

    __shared__ float red[4][UG][64];
    #pragma unroll
    for (int u = 0; u < UG; ++u) red[w][u][d] = acc[u];
    __syncthreads();

    for (int i = t; i < UG * 64; i += 256) {
        int u = i >> 6, dd = i & 63;
        float s = red[0][u][dd] + red[1][u][dd] + red[2][u][dd] + red[3][u][dd];
        partial[(((size_t)bh * U + ug * UG + u) * RCH + rch) * 64 + dd] = s;
    }
}

// ---------------------------------------------------------------------------
// Kernel 3c stage 2: reduce partials and scatter into out.
// ---------------------------------------------------------------------------
__global__ void pv_reduce_kernel(const float* __restrict__ partial, const int* __restrict__ Mtop,
                                 float* __restrict__ out) {
    int idx = blockIdx.x * 256 + threadIdx.x;   // 0 .. B*H*U*64-1
    int dd = idx & 63;
    int bhu = idx >> 6;                          // 0..2559
    int bh = bhu / U;
    int b = bh / H, h = bh % H;

    const float* pp = partial + (size_t)bhu * RCH * 64 + dd;
    float s = 0.f;
    #pragma unroll
    for (int c = 0; c < RCH; ++c) s += pp[c * 64];

    int qi = Mtop[bhu];
    out[((size_t)(b * L + qi) * H + h) * D + dd] = s;
}

// ---------------------------------------------------------------------------
// Old single-stage PV (fallback if partial buffer doesn't fit).
// ---------------------------------------------------------------------------
__global__ void pv_kernel(const float* __restrict__ v, const float* __restrict__ p,
                          const int* __restrict__ Mtop, float* __restrict__ out) {
    int blk = blockIdx.x;
    int xcd = blk & 7;
    int rest = blk >> 3;
    int bh_hi = rest & 7;
    int ug = rest >> 3;
    int bh = bh_hi * 8 + xcd;
    int b = bh / H, h = bh % H;
    int t = threadIdx.x;
    int d = t & 63;
    int w = t >> 6;

    const float* pb = p + ((size_t)bh * U + (size_t)ug * UG) * L;
    float acc[UG];
    #pragma unroll
    for (int u = 0; u < UG; ++u) acc[u] = 0.f;

    for (int r = w * 512; r < (w + 1) * 512; ++r) {
        float vv = v[((size_t)(b * L + r)) * H * D + h * D + d];
        #pragma unroll
        for (int u = 0; u < UG; ++u) acc[u] += pb[(size_t)u * L + r] * vv;
    }

    __shared__ float red[4][UG][64];
    #pragma unroll
    for (int u = 0; u < UG; ++u) red[w][u][d] = acc[u];
    __syncthreads();

    for (int i = t; i < UG * 64; i += 256) {
        int u = i >> 6, dd = i & 63;
        float s = red[0][u][dd] + red[1][u][dd] + red[2][u][dd] + red[3][u][dd];
        int qi = Mtop[bh * U + ug * UG + u];
        out[((size_t)(b * L + qi)) * H * D + h * D + dd] = s;
    }
}

// ---------------------------------------------------------------------------
// Fallback attention if workspace too small for the score buffer.
// ---------------------------------------------------------------------------
__global__ void attn_kernel_fallback(const float* __restrict__ q, const float* __restrict__ k,
                                     const float* __restrict__ v, const int* __restrict__ Mtop,
                                     float* __restrict__ out) {
    int blk = blockIdx.x;
    int bh = blk / U;
    int u = blk % U;
    int b = bh / H;
    int h = bh % H;
    int qi = Mtop[bh * U + u];

    __shared__ float sc[L];
    __shared__ float qs[D];
    __shared__ float red[4];
    __shared__ float ctx_s[4][D];

    int t = threadIdx.x;
    if (t < D) qs[t] = q[((size_t)(b * L + qi)) * H * D + h * D + t];
    __syncthreads();

    float lm = -FLT_MAX;
    for (int i = t; i < L; i += 256) {
        const float* krow = k + ((size_t)(b * L + i)) * H * D + h * D;
        float acc = 0.f;
        #pragma unroll
        for (int dd = 0; dd < D; ++dd) acc += qs[dd] * krow[dd];
        acc *= 0.125f;
        sc[i] = acc;
        lm = fmaxf(lm, acc);
    }
    #pragma unroll
    for (int off = 32; off >= 1; off >>= 1) lm = fmaxf(lm, __shfl_xor(lm, off));
    if ((t & 63) == 0) red[t >> 6] = lm;
    __syncthreads();
    float gm = fmaxf(fmaxf(red[0], red[1]), fmaxf(red[2], red[3]));

    float ls = 0.f;
    for (int i = t; i < L; i += 256) {
        float e = expf(sc[i] - gm);
        sc[i] = e;
        ls += e;
    }
    #pragma unroll
    for (int off = 32; off >= 1; off >>= 1) ls += __shfl_xor(ls, off);
    __syncthreads();
    if ((t & 63) == 0) red[t >> 6] = ls;
    __syncthreads();
    float inv = 1.0f / (red[0] + red[1] + red[2] + red[3]);

    int d = t & 63;
    int g = t >> 6;
    float acc = 0.f;
    for (int i = g; i < L; i += 4) {
        acc += sc[i] * v[((size_t)(b * L + i)) * H * D + h * D + d];
    }
    ctx_s[g][d] = acc;
    __syncthreads();
    if (g == 0) {
        float c = (ctx_s[0][d] + ctx_s[1][d] + ctx_s[2][d] + ctx_s[3][d]) * inv;
        out[((size_t)(b * L + qi)) * H * D + h * D + d] = c;
    }
}

// ---------------------------------------------------------------------------
extern "C" void kernel_launch(void* const* d_in, const int* in_sizes, int n_in,
                              void* d_out, int out_size, void* d_ws, size_t ws_size,
                              hipStream_t stream) {
    const float* q = (const float*)d_in[0];
    const float* k = (const float*)d_in[1];
    const float* v = (const float*)d_in[2];
    const int* sidx = (const int*)d_in[3];
    float* out = (float*)d_out;

    int SK = in_sizes[3] / L;  // sample_k (40 for this shape)

    // Workspace layout
    size_t offM = 0;                                        // B*H*L floats
    size_t offMtop = offM + (size_t)B * H * L * sizeof(float);
    size_t offSc = offMtop + (size_t)B * H * U * sizeof(int);
    offSc = (offSc + 255) & ~(size_t)255;
    size_t offPart = offSc + (size_t)B * H * U * L * sizeof(float);
    offPart = (offPart + 255) & ~(size_t)255;
    size_t needSc = offPart;                                // through sc
    size_t needAll = offPart + (size_t)B * H * U * RCH * 64 * sizeof(float);

    float* M = (float*)((char*)d_ws + offM);
    int* Mtop = (int*)((char*)d_ws + offMtop);
    float* sc = (float*)((char*)d_ws + offSc);
    float* partial = (float*)((char*)d_ws + offPart);

    int n4 = (B * L * H * D) / 4;

    if (SK == 40) {
        fused_copy_M_kernel<40><<<NGRP * 8, 256, 0, stream>>>(q, k, v, sidx, out, M, n4);
    } else {
        copy_v_kernel<<<2048, 256, 0, stream>>>(v, out, n4);
        compute_M_kernel<<<B * L, 256, 0, stream>>>(q, k, sidx, M, SK);
    }
    topk_wave_kernel<<<B * H, 64, 0, stream>>>(M, Mtop);

    if (ws_size >= needSc) {
        scores_kernel<<<B * H * NCH, 256, 0, stream>>>(q, k, Mtop, sc);
        softmax_kernel<<<B * H * U, 256, 0, stream>>>(sc);
        if (ws_size >= needAll) {
            pv_partial_kernel<<<B * H * (U / UG) * RCH, 256, 0, stream>>>(v, sc, partial);
            pv_reduce_kernel<<<B * H * U * 64 / 256, 256, 0, stream>>>(partial, Mtop, out);
        } else {
            pv_kernel<<<B * H * (U / UG), 256, 0, stream>>>(v, sc, Mtop, out);
        }
    } else {
        attn_kernel_fallback<<<B * H * U, 256, 0, stream>>>(q, k, v, Mtop, out);
    }
}